// Round 12
// baseline (151.341 us; speedup 1.0000x reference)
//
#include <hip/hip_runtime.h>

#define NN 8000
#define NPAD 8064
#define NE 64000
#define INF 16
#define HH 128
#define MM 16
#define EDF 4
#define OUTF 4
#define NL 2
#define BN_EPS 1e-5f
#define BPR 2080          // Bp rows (layer 1 only): 2048 qn + 16 b2 + 16 rootW
#define CAP 48            // per-node edge bucket capacity

typedef __attribute__((ext_vector_type(8))) short short8;
typedef __attribute__((ext_vector_type(4))) float f32x4;

static __device__ __forceinline__ unsigned short f2bf(float f) {
  unsigned u = __builtin_bit_cast(unsigned, f);
  u = (u + 0x7fffu + ((u >> 16) & 1u)) >> 16;
  return (unsigned short)u;
}
static __device__ __forceinline__ float bf2f(unsigned short s) {
  unsigned u = ((unsigned)s) << 16;
  return __builtin_bit_cast(float, u);
}

// bijective k-permutation for contract LDS layout, and its inverse
static __device__ __forceinline__ int qperm(int k) {
  return ((k >> 3) & 3) | ((k & 7) << 2) | (k & 0x60);
}
static __device__ __forceinline__ int qinv(int r) {
  return ((r & 3) << 3) | ((r >> 2) & 7) | (r & 0x60);
}

// K0: layer-0 GEMM (A = x@inW inline; B from W2/b2/rW direct) [blocks 0..566]
//   + edge bucket-scatter [567..816] + agg zero [817..941] + Bp(layer1) build [942..1071]
__global__ __launch_bounds__(256) void k0_k(
    const float* __restrict__ x, const float* __restrict__ inW,
    const float* __restrict__ inb, const int* __restrict__ ei,
    const float* __restrict__ ea,
    const float* __restrict__ W2, const float* __restrict__ b2,
    const float* __restrict__ rW,
    unsigned short* __restrict__ hb,
    float* __restrict__ deg, int* __restrict__ cnt,
    unsigned short* __restrict__ Bp, float* __restrict__ agg,
    float* __restrict__ ea_s, int* __restrict__ dst_s,
    unsigned short* __restrict__ Qn, float* __restrict__ B2,
    float* __restrict__ Xroot) {
  __shared__ unsigned short sA[16384];
  __shared__ unsigned short sB[16384];
  __shared__ float sIW[INF * HH];
  __shared__ float sIB[HH];
  int blk = blockIdx.x;
  int tid = threadIdx.x;

  if (blk < 567) {
    int bm = blk / 9, bn = blk - bm * 9;
    int r0 = bm * 128;

    // stage inW + inb
    for (int i = tid; i < INF * HH; i += 256) sIW[i] = inW[i];
    if (tid < HH) sIB[tid] = inb[tid];
    __syncthreads();

    // ---- A compute: row rl = tid>>1, slots k8 = (tid&1)*8 .. +8 ----
    {
      int rl = tid >> 1;
      int n = r0 + rl;
      int k8b = (tid & 1) * 8;
      float xr[16];
      if (n < NN) {
#pragma unroll
        for (int q = 0; q < 4; ++q)
          *(float4*)&xr[q * 4] = *(const float4*)&x[(size_t)n * INF + q * 4];
      } else {
#pragma unroll
        for (int q = 0; q < 16; ++q) xr[q] = 0.f;
      }
#pragma unroll
      for (int rr = 0; rr < 8; ++rr) {
        int k8 = k8b + rr;
        short8 o = {0, 0, 0, 0, 0, 0, 0, 0};
        if (n < NN) {
#pragma unroll
          for (int j = 0; j < 8; ++j) {
            int c = k8 * 8 + j;
            float acc = sIB[c];
#pragma unroll
            for (int i = 0; i < INF; ++i) acc = fmaf(xr[i], sIW[i * HH + c], acc);
            o[j] = (short)f2bf(acc);
          }
          if (bn == 0)
            *(uint4*)&hb[(size_t)n * HH + k8 * 8] = __builtin_bit_cast(uint4, o);
        }
        *(short8*)&sA[(rl * 16 + (k8 ^ (rl & 7))) * 8] = o;
      }
    }

    int wid = tid >> 6, lane = tid & 63;
    int wr = (wid >> 1) * 64;
    int wc = (wid & 1) * 64;
    int l15 = lane & 15, l4 = lane >> 4;

    int nchunk = (bn < 8) ? 2 : 1;
    for (int half = 0; half < nchunk; ++half) {
      int chunk = (bn < 8) ? (bn * 2 + half) : 16;

      if (chunk < 16) {
        // B from W2 rows k = chunk*8 .. +8 (contiguous 64KB f32), transposed
        const float* w2c = W2 + (size_t)chunk * 8 * 2048;
#pragma unroll
        for (int it = 0; it < 16; ++it) {
          int i4 = it * 256 + tid;
          float4 v = ((const float4*)w2c)[i4];
          int idx = i4 * 4;
          int k = idx >> 11;
          int rem = idx & 2047;
          int h = rem >> 4, m0 = rem & 15;
#pragma unroll
          for (int j = 0; j < 4; ++j) {
            int crow = k * 16 + m0 + j;
            sB[(crow * 16 + ((h >> 3) ^ (crow & 7))) * 8 + (h & 7)] = f2bf((&v.x)[j]);
          }
        }
      } else {
        // rows 0..15 = b2^T, 16..31 = rW^T, 32..127 zero
        uint4 z = make_uint4(0, 0, 0, 0);
#pragma unroll
        for (int i = 0; i < 6; ++i) *(uint4*)&sB[(512 + i * 256 + tid) * 8] = z;
#pragma unroll
        for (int it = 0; it < 2; ++it) {
          int i4 = it * 256 + tid;
          float4 v = ((const float4*)b2)[i4];
          int idx = i4 * 4;
          int h = idx >> 4, m0 = idx & 15;
#pragma unroll
          for (int j = 0; j < 4; ++j) {
            int crow = m0 + j;
            sB[(crow * 16 + ((h >> 3) ^ (crow & 7))) * 8 + (h & 7)] = f2bf((&v.x)[j]);
          }
        }
#pragma unroll
        for (int it = 0; it < 2; ++it) {
          int i4 = it * 256 + tid;
          float4 v = ((const float4*)rW)[i4];
          int idx = i4 * 4;
          int h = idx >> 4, m0 = idx & 15;
#pragma unroll
          for (int j = 0; j < 4; ++j) {
            int crow = 16 + m0 + j;
            sB[(crow * 16 + ((h >> 3) ^ (crow & 7))) * 8 + (h & 7)] = f2bf((&v.x)[j]);
          }
        }
      }
      __syncthreads();

      f32x4 acc[4][4] = {};
#pragma unroll
      for (int ks = 0; ks < 4; ++ks) {
        short8 af[4], bfr[4];
        int kb = ks * 4 + l4;
#pragma unroll
        for (int mr = 0; mr < 4; ++mr) {
          int r = wr + mr * 16 + l15;
          af[mr] = *(const short8*)&sA[(r * 16 + (kb ^ (r & 7))) * 8];
        }
#pragma unroll
        for (int nc = 0; nc < 4; ++nc) {
          int r = wc + nc * 16 + l15;
          bfr[nc] = *(const short8*)&sB[(r * 16 + (kb ^ (r & 7))) * 8];
        }
#pragma unroll
        for (int mr = 0; mr < 4; ++mr)
#pragma unroll
          for (int nc = 0; nc < 4; ++nc)
            acc[mr][nc] = __builtin_amdgcn_mfma_f32_16x16x32_bf16(af[mr], bfr[nc], acc[mr][nc], 0, 0, 0);
      }

      if (chunk < 16) {
#pragma unroll
        for (int mr = 0; mr < 4; ++mr) {
          int rr0 = r0 + wr + mr * 16 + l4 * 4;
#pragma unroll
          for (int nc = 0; nc < 4; ++nc) {
            int c0 = chunk * 128 + wc + nc * 16 + l15;
#pragma unroll
            for (int j = 0; j < 4; ++j)
              Qn[(size_t)(rr0 + j) * (HH * MM) + c0] = f2bf(acc[mr][nc][j]);
          }
        }
      } else if (wc == 0) {
#pragma unroll
        for (int mr = 0; mr < 4; ++mr) {
          int rr0 = r0 + wr + mr * 16 + l4 * 4;
#pragma unroll
          for (int j = 0; j < 4; ++j) {
            B2[(size_t)(rr0 + j) * MM + l15] = acc[mr][0][j];
            Xroot[(size_t)(rr0 + j) * MM + l15] = acc[mr][1][j];
          }
        }
      }
      __syncthreads();
    }
  } else if (blk < 817) {
    int e = (blk - 567) * 256 + tid;   // 250*256 = 64000 exact
    int src = ei[e], dst = ei[NE + e];
    atomicAdd(&deg[dst], 1.0f);
    int slot = atomicAdd(&cnt[src], 1);
    int p = src * CAP + slot;
    *(float4*)&ea_s[(size_t)p * 4] = *(const float4*)&ea[(size_t)e * 4];
    dst_s[p] = dst;
  } else if (blk < 942) {
    int i = (blk - 817) * 256 + tid;   // 125*256 = 32000 uint4 = NN*MM f32
    ((uint4*)agg)[i] = make_uint4(0, 0, 0, 0);
  } else {
    int r = blk - 942;                 // 0..129 ; layer-1 Bp build
    if (tid < 128) {
      const float* src;
      unsigned short* bpr;
      if (r < 128) {
        src = W2 + (size_t)HH * HH * MM + (size_t)r * 2048;
        bpr = Bp + ((size_t)r * 16) * HH + tid;
      } else if (r == 128) {
        src = b2 + 2048;
        bpr = Bp + (size_t)2048 * HH + tid;
      } else {
        src = rW + (size_t)HH * MM;
        bpr = Bp + (size_t)2064 * HH + tid;
      }
      float4 v0 = *(const float4*)&src[tid * 16 + 0];
      float4 v1 = *(const float4*)&src[tid * 16 + 4];
      float4 v2 = *(const float4*)&src[tid * 16 + 8];
      float4 v3 = *(const float4*)&src[tid * 16 + 12];
#pragma unroll
      for (int j = 0; j < 4; ++j) bpr[(0 + j) * HH] = f2bf((&v0.x)[j]);
#pragma unroll
      for (int j = 0; j < 4; ++j) bpr[(4 + j) * HH] = f2bf((&v1.x)[j]);
#pragma unroll
      for (int j = 0; j < 4; ++j) bpr[(8 + j) * HH] = f2bf((&v2.x)[j]);
#pragma unroll
      for (int j = 0; j < 4; ++j) bpr[(12 + j) * HH] = f2bf((&v3.x)[j]);
    }
  }
}

// Layer-1 GEMM: Qn = BN_relu(hpre) @ Bp^T ; grid (9, 63). bn==8 -> B2/Xroot chunk.
__global__ __launch_bounds__(256) void gemm_qn_k(
    const float* __restrict__ hpre,
    const float* __restrict__ bnsums, const float* __restrict__ gamma,
    const float* __restrict__ beta,
    const unsigned short* __restrict__ Bp,
    unsigned short* __restrict__ Qn, float* __restrict__ B2,
    float* __restrict__ Xroot) {
  __shared__ unsigned short sA[16384];
  __shared__ unsigned short sB[16384];
  int tid = threadIdx.x;
  int bm = blockIdx.y, bn = blockIdx.x;
  int r0 = bm * 128;

  // ---- A staging: BN_relu(hpre) -> bf16, swizzled ----
  {
    int k8 = tid & 15;
    int c0 = k8 * 8;
    float scl[8], shf[8];
#pragma unroll
    for (int j = 0; j < 8; ++j) {
      int c = c0 + j;
      float mu = bnsums[c] * (1.0f / NN);
      float var = bnsums[HH + c] * (1.0f / NN) - mu * mu;
      float sc = gamma[c] * rsqrtf(var + BN_EPS);
      scl[j] = sc;
      shf[j] = beta[c] - mu * sc;
    }
#pragma unroll
    for (int rr = 0; rr < 8; ++rr) {
      int s = rr * 256 + tid;
      int row = s >> 4;
      int n = r0 + row;
      short8 o = {0, 0, 0, 0, 0, 0, 0, 0};
      if (n < NN) {
        float4 v0 = *(const float4*)&hpre[(size_t)n * HH + c0];
        float4 v1 = *(const float4*)&hpre[(size_t)n * HH + c0 + 4];
#pragma unroll
        for (int j = 0; j < 4; ++j) {
          o[j] = (short)f2bf(fmaxf(0.f, fmaf((&v0.x)[j], scl[j], shf[j])));
          o[4 + j] = (short)f2bf(fmaxf(0.f, fmaf((&v1.x)[j], scl[4 + j], shf[4 + j])));
        }
      }
      *(short8*)&sA[(s ^ ((s >> 4) & 7)) * 8] = o;
    }
  }

  int wid = tid >> 6, lane = tid & 63;
  int wr = (wid >> 1) * 64;
  int wc = (wid & 1) * 64;
  int l15 = lane & 15, l4 = lane >> 4;

  int nchunk = (bn < 8) ? 2 : 1;
  for (int half = 0; half < nchunk; ++half) {
    int chunk = (bn < 8) ? (bn * 2 + half) : 16;

    if (chunk < 16) {
      const uint4* gB = (const uint4*)(Bp + (size_t)chunk * 128 * HH);
#pragma unroll
      for (int rr = 0; rr < 8; ++rr) {
        int s = rr * 256 + tid;
        uint4 v = gB[s];
        *(uint4*)&sB[(s ^ ((s >> 4) & 7)) * 8] = v;
      }
    } else {
      const uint4* gB = (const uint4*)(Bp + (size_t)2048 * HH);
#pragma unroll
      for (int rr = 0; rr < 8; ++rr) {
        int s = rr * 256 + tid;
        int row = s >> 4;
        uint4 v = make_uint4(0, 0, 0, 0);
        if (row < 32) v = gB[s];
        *(uint4*)&sB[(s ^ ((s >> 4) & 7)) * 8] = v;
      }
    }
    __syncthreads();

    f32x4 acc[4][4] = {};
#pragma unroll
    for (int ks = 0; ks < 4; ++ks) {
      short8 af[4], bfr[4];
      int kb = ks * 4 + l4;
#pragma unroll
      for (int mr = 0; mr < 4; ++mr) {
        int r = wr + mr * 16 + l15;
        af[mr] = *(const short8*)&sA[(r * 16 + (kb ^ (r & 7))) * 8];
      }
#pragma unroll
      for (int nc = 0; nc < 4; ++nc) {
        int r = wc + nc * 16 + l15;
        bfr[nc] = *(const short8*)&sB[(r * 16 + (kb ^ (r & 7))) * 8];
      }
#pragma unroll
      for (int mr = 0; mr < 4; ++mr)
#pragma unroll
        for (int nc = 0; nc < 4; ++nc)
          acc[mr][nc] = __builtin_amdgcn_mfma_f32_16x16x32_bf16(af[mr], bfr[nc], acc[mr][nc], 0, 0, 0);
    }

    if (chunk < 16) {
#pragma unroll
      for (int mr = 0; mr < 4; ++mr) {
        int rr0 = r0 + wr + mr * 16 + l4 * 4;
#pragma unroll
        for (int nc = 0; nc < 4; ++nc) {
          int c0 = chunk * 128 + wc + nc * 16 + l15;
#pragma unroll
          for (int j = 0; j < 4; ++j)
            Qn[(size_t)(rr0 + j) * (HH * MM) + c0] = f2bf(acc[mr][nc][j]);
        }
      }
    } else if (wc == 0) {
#pragma unroll
      for (int mr = 0; mr < 4; ++mr) {
        int rr0 = r0 + wr + mr * 16 + l4 * 4;
#pragma unroll
        for (int j = 0; j < 4; ++j) {
          B2[(size_t)(rr0 + j) * MM + l15] = acc[mr][0][j];
          Xroot[(size_t)(rr0 + j) * MM + l15] = acc[mr][1][j];
        }
      }
    }
    __syncthreads();
  }
}

// One wave per src node: P[d x 16] = relu1[d x 128] @ Qn[n][128 x 16] via MFMA.
__global__ __launch_bounds__(256) void contract_k(const float* __restrict__ ea_s,
                                                  const int* __restrict__ dst_s,
                                                  const int* __restrict__ cnt,
                                                  const float* __restrict__ W1,
                                                  const float* __restrict__ b1,
                                                  const unsigned short* __restrict__ Qn,
                                                  const float* __restrict__ B2,
                                                  float* __restrict__ agg) {
  __shared__ float sW1[EDF * HH];
  __shared__ float sb1[HH];
  __shared__ unsigned short sQ[4][HH * MM];
  int tid = threadIdx.x;
  for (int i = tid; i < EDF * HH; i += 256) sW1[i] = W1[i];
  if (tid < HH) sb1[tid] = b1[tid];
  __syncthreads();

  int wid = tid >> 6, lane = tid & 63;
  int n = blockIdx.x * 4 + wid;
  int l15 = lane & 15, l4 = lane >> 4;
  int count = cnt[n];
  if (count == 0) return;

  {
    const unsigned short* q = Qn + (size_t)n * (HH * MM);
#pragma unroll
    for (int i = 0; i < 4; ++i) {
      int r = i * 32 + (lane >> 1);
      int c = (lane & 1) * 8;
      uint4 v = *(const uint4*)(q + qinv(r) * 16 + c);
      *(uint4*)&sQ[wid][i * 512 + lane * 8] = v;
    }
  }
  float b2v = B2[(size_t)n * MM + l15];
  __builtin_amdgcn_s_waitcnt(0);

  const float* eab = ea_s + (size_t)n * CAP * 4;
  const int* dsb = dst_s + (size_t)n * CAP;
  for (int t0 = 0; t0 < count; t0 += 16) {
    int rr = t0 + l15;
    bool valid = rr < count;
    float4 eav = valid ? *(const float4*)&eab[(size_t)rr * 4]
                       : make_float4(0.f, 0.f, 0.f, 0.f);
    f32x4 acc = {0.f, 0.f, 0.f, 0.f};
#pragma unroll
    for (int ks = 0; ks < 4; ++ks) {
      short8 a, b;
#pragma unroll
      for (int j = 0; j < 8; ++j) {
        int k = ks * 32 + l4 * 8 + j;
        float r = fmaf(eav.w, sW1[3 * HH + k],
                   fmaf(eav.z, sW1[2 * HH + k],
                     fmaf(eav.y, sW1[HH + k], fmaf(eav.x, sW1[k], sb1[k]))));
        a[j] = valid ? (short)f2bf(fmaxf(r, 0.f)) : (short)0;
        b[j] = (short)sQ[wid][qperm(k) * 16 + l15];
      }
      acc = __builtin_amdgcn_mfma_f32_16x16x32_bf16(a, b, acc, 0, 0, 0);
    }
#pragma unroll
    for (int j = 0; j < 4; ++j) {
      int r = t0 + l4 * 4 + j;
      if (r < count) {
        atomicAdd(&agg[(size_t)dst_s[(size_t)n * CAP + r] * MM + l15], acc[j] + b2v);
      }
    }
    (void)dsb;
  }
}

// 16 nodes/block: xm = agg/deg + Xroot + cbias ; hp = resid + xm@msgW + msgb
// fused BN partial sums; zeroes its agg slice for next layer.
__global__ __launch_bounds__(256) void node_update_k(
    const unsigned short* __restrict__ hb, const float* __restrict__ hsrc_pre,
    const float* __restrict__ bnsums, const float* __restrict__ gamma,
    const float* __restrict__ beta, int bn_mode,
    float* __restrict__ agg, const float* __restrict__ deg,
    const float* __restrict__ Xroot, const float* __restrict__ cbias,
    const float* __restrict__ msgW, const float* __restrict__ msgb,
    float* __restrict__ hpre, float* __restrict__ sums) {
  __shared__ float smw[MM * HH];
  __shared__ float xm[16][MM];
  __shared__ float scb[MM];
  __shared__ float smb[HH];
  __shared__ float red[256];
  __shared__ float sscl[HH], sshf[HH];
  int tid = threadIdx.x;
  int n0 = blockIdx.x * 16;
  for (int i = tid; i < MM * HH; i += 256) smw[i] = msgW[i];
  if (tid < MM) scb[tid] = cbias[tid];
  if (tid < HH) smb[tid] = msgb[tid];
  if (bn_mode && tid < HH) {
    float mu = bnsums[tid] * (1.0f / NN);
    float var = bnsums[HH + tid] * (1.0f / NN) - mu * mu;
    float sc = gamma[tid] * rsqrtf(var + BN_EPS);
    sscl[tid] = sc;
    sshf[tid] = beta[tid] - mu * sc;
  }
  __syncthreads();

  {
    int ni = tid >> 4, m = tid & 15;
    int n = n0 + ni;
    size_t idx = (size_t)n * MM + m;
    xm[ni][m] = agg[idx] / fmaxf(deg[n], 1.0f) + Xroot[idx] + scb[m];
  }
  __syncthreads();
  agg[(size_t)n0 * MM + tid] = 0.f;

  int t = tid & 127;
  float lsum = 0.f, lss = 0.f;
#pragma unroll
  for (int pass = 0; pass < 8; ++pass) {
    int ni = pass * 2 + (tid >> 7);
    size_t idx = (size_t)(n0 + ni) * HH + t;
    float resid;
    if (bn_mode) {
      resid = fmaxf(0.f, fmaf(hsrc_pre[idx], sscl[t], sshf[t]));
    } else {
      resid = bf2f(hb[idx]);
    }
    float hp = resid + smb[t];
#pragma unroll
    for (int m = 0; m < MM; ++m) hp = fmaf(xm[ni][m], smw[m * HH + t], hp);
    hpre[idx] = hp;
    lsum += hp;
    lss = fmaf(hp, hp, lss);
  }
  red[tid] = lsum;
  __syncthreads();
  if (tid < 128) atomicAdd(&sums[t], red[tid] + red[tid + 128]);
  __syncthreads();
  red[tid] = lss;
  __syncthreads();
  if (tid < 128) atomicAdd(&sums[HH + t], red[tid] + red[tid + 128]);
}

__global__ void out_proj_k(const float* __restrict__ hpre,
                           const float* __restrict__ bnsums,
                           const float* __restrict__ gamma,
                           const float* __restrict__ beta,
                           const float* __restrict__ W, const float* __restrict__ b,
                           float* __restrict__ out) {
  __shared__ float sscl[HH], sshf[HH];
  int tid = threadIdx.x;
  if (tid < HH) {
    float mu = bnsums[tid] * (1.0f / NN);
    float var = bnsums[HH + tid] * (1.0f / NN) - mu * mu;
    float sc = gamma[tid] * rsqrtf(var + BN_EPS);
    sscl[tid] = sc;
    sshf[tid] = beta[tid] - mu * sc;
  }
  __syncthreads();
  int n = blockIdx.x * 4 + (tid >> 6);
  int lane = tid & 63;
  if (n >= NN) return;
  float acc0 = 0.f, acc1 = 0.f, acc2 = 0.f, acc3 = 0.f;
#pragma unroll
  for (int rep = 0; rep < 2; ++rep) {
    int hh = lane + rep * 64;
    float hv = fmaxf(0.f, fmaf(hpre[(size_t)n * HH + hh], sscl[hh], sshf[hh]));
    acc0 = fmaf(hv, W[hh * OUTF + 0], acc0);
    acc1 = fmaf(hv, W[hh * OUTF + 1], acc1);
    acc2 = fmaf(hv, W[hh * OUTF + 2], acc2);
    acc3 = fmaf(hv, W[hh * OUTF + 3], acc3);
  }
#pragma unroll
  for (int s = 32; s > 0; s >>= 1) {
    acc0 += __shfl_down(acc0, s);
    acc1 += __shfl_down(acc1, s);
    acc2 += __shfl_down(acc2, s);
    acc3 += __shfl_down(acc3, s);
  }
  if (lane == 0) {
    out[n * OUTF + 0] = acc0 + b[0];
    out[n * OUTF + 1] = acc1 + b[1];
    out[n * OUTF + 2] = acc2 + b[2];
    out[n * OUTF + 3] = acc3 + b[3];
  }
}

extern "C" void kernel_launch(void* const* d_in, const int* in_sizes, int n_in,
                              void* d_out, int out_size, void* d_ws, size_t ws_size,
                              hipStream_t stream) {
  (void)in_sizes; (void)n_in; (void)out_size; (void)ws_size;
  const float* x    = (const float*)d_in[0];
  const int* ei     = (const int*)d_in[1];
  const float* ea   = (const float*)d_in[2];
  const float* inW  = (const float*)d_in[3];
  const float* inb  = (const float*)d_in[4];
  const float* cW1  = (const float*)d_in[5];
  const float* cb1  = (const float*)d_in[6];
  const float* cW2  = (const float*)d_in[7];
  const float* cb2  = (const float*)d_in[8];
  const float* rW   = (const float*)d_in[9];
  const float* cbias= (const float*)d_in[10];
  const float* gam  = (const float*)d_in[11];
  const float* bet  = (const float*)d_in[12];
  const float* mW   = (const float*)d_in[13];
  const float* mb   = (const float*)d_in[14];
  const float* oW   = (const float*)d_in[15];
  const float* ob   = (const float*)d_in[16];
  float* out = (float*)d_out;

  float* ws = (float*)d_ws;
  size_t off = 0;
  // contiguous zero region: deg, cnt, sums0, sums1 (one small memset)
  float* deg   = ws + off; off += 8192;
  int* cnt     = (int*)(ws + off); off += 8192;
  float* sums0 = ws + off; off += 256;
  float* sums1 = ws + off; off += 256;
  size_t zero_floats = off;
  float* agg   = ws + off; off += (size_t)NN * MM;      // zeroed by k0
  float* hpre0 = ws + off; off += (size_t)NN * HH;
  float* hpre1 = ws + off; off += (size_t)NN * HH;
  float* B2    = ws + off; off += (size_t)NPAD * MM;
  float* Xroot = ws + off; off += (size_t)NPAD * MM;
  unsigned short* hb = (unsigned short*)(ws + off); off += (size_t)NN * HH / 2;
  unsigned short* Bp = (unsigned short*)(ws + off); off += (size_t)BPR * HH / 2;
  unsigned short* Qn = (unsigned short*)(ws + off); off += (size_t)NPAD * HH * MM / 2;
  float* ea_s  = ws + off; off += (size_t)NN * CAP * 4;
  int* dst_s   = (int*)(ws + off); off += (size_t)NN * CAP;

  hipMemsetAsync(deg, 0, zero_floats * sizeof(float), stream);
  // K0: layer-0 gemm + in_proj(hb) + edge scatter + agg zero + Bp(layer1) build
  k0_k<<<1072, 256, 0, stream>>>(x, inW, inb, ei, ea, cW2, cb2, rW, hb,
                                 deg, cnt, Bp, agg, ea_s, dst_s, Qn, B2, Xroot);
  contract_k<<<NN / 4, 256, 0, stream>>>(ea_s, dst_s, cnt, cW1, cb1, Qn, B2, agg);
  node_update_k<<<NN / 16, 256, 0, stream>>>(hb, hpre0, sums0, gam, bet, 0,
                                             agg, deg, Xroot, cbias, mW, mb,
                                             hpre0, sums0);
  // ---- layer 1 ----
  dim3 gg(9, NPAD / 128);
  gemm_qn_k<<<gg, 256, 0, stream>>>(hpre0, sums0, gam, bet, Bp, Qn, B2, Xroot);
  contract_k<<<NN / 4, 256, 0, stream>>>(ea_s, dst_s, cnt, cW1 + EDF * HH,
                                         cb1 + HH, Qn, B2, agg);
  node_update_k<<<NN / 16, 256, 0, stream>>>(hb, hpre0, sums0, gam, bet, 1,
                                             agg, deg, Xroot, cbias + MM,
                                             mW + MM * HH, mb + HH,
                                             hpre1, sums1);
  out_proj_k<<<NN / 4, 256, 0, stream>>>(hpre1, sums1, gam + HH, bet + HH,
                                         oW, ob, out);
}